// Round 4
// baseline (570.629 us; speedup 1.0000x reference)
//
#include <hip/hip_runtime.h>
#include <math.h>

#define T 2048
#define HD 1024
#define ID 2048
#define NE 8

typedef short bf16x8 __attribute__((ext_vector_type(8)));
typedef float f32x4 __attribute__((ext_vector_type(4)));
typedef unsigned short u16x8 __attribute__((ext_vector_type(8)));

__device__ __forceinline__ unsigned short f2bf(float f) {
  union { float f; unsigned u; } v; v.f = f;
  unsigned r = v.u + 0x7FFFu + ((v.u >> 16) & 1u);
  return (unsigned short)(r >> 16);
}

__device__ __forceinline__ u16x8 cvt8(float4 a, float4 b) {
  u16x8 o;
  o[0] = f2bf(a.x); o[1] = f2bf(a.y); o[2] = f2bf(a.z); o[3] = f2bf(a.w);
  o[4] = f2bf(b.x); o[5] = f2bf(b.y); o[6] = f2bf(b.z); o[7] = f2bf(b.w);
  return o;
}

// async global->LDS, 16B per lane; LDS dest = wave-uniform base + lane*16
__device__ __forceinline__ void glds16(const unsigned short* g, unsigned short* l) {
  __builtin_amdgcn_global_load_lds(
      (const __attribute__((address_space(1))) unsigned int*)(g),
      (__attribute__((address_space(3))) unsigned int*)(l), 16, 0, 0);
}

// ---------- cast x (fp32) -> xb (bf16) ----------
__global__ __launch_bounds__(256) void cast_x_kernel(
    const float* __restrict__ x, unsigned short* __restrict__ xb) {
  size_t idx = ((size_t)blockIdx.x * 256 + threadIdx.x) * 8;
  float4 f0 = *(const float4*)(x + idx);
  float4 f1 = *(const float4*)(x + idx + 4);
  *(u16x8*)(xb + idx) = cvt8(f0, f1);
}

// ---------- cast weights (fp32) -> bf16, 3 tensors via blockIdx.y ----------
__global__ __launch_bounds__(256) void cast_w_kernel(
    const float* __restrict__ s0, const float* __restrict__ s1,
    const float* __restrict__ s2, unsigned short* __restrict__ d0,
    unsigned short* __restrict__ d1, unsigned short* __restrict__ d2) {
  const float* s; unsigned short* d;
  if (blockIdx.y == 0)      { s = s0; d = d0; }
  else if (blockIdx.y == 1) { s = s1; d = d1; }
  else                      { s = s2; d = d2; }
  size_t idx = ((size_t)blockIdx.x * 256 + threadIdx.x) * 8;
  float4 f0 = *(const float4*)(s + idx);
  float4 f1 = *(const float4*)(s + idx + 4);
  *(u16x8*)(d + idx) = cvt8(f0, f1);
}

// ---------- router ----------
__global__ __launch_bounds__(256) void router_kernel(
    const float* __restrict__ x, const float* __restrict__ rw,
    float* __restrict__ logits_out, int* __restrict__ pair_rowid,
    float* __restrict__ pair_gate, int* __restrict__ counts) {
  __shared__ float rws[NE * HD];
  int tid = threadIdx.x;
  for (int j = tid * 4; j < NE * HD; j += 256 * 4)
    *(float4*)&rws[j] = *(const float4*)&rw[j];
  __syncthreads();
  int wid = tid >> 6, lane = tid & 63;
  int t = blockIdx.x * 4 + wid;
  float acc[NE];
#pragma unroll
  for (int e = 0; e < NE; e++) acc[e] = 0.f;
  const float* xrow = x + (size_t)t * HD;
  for (int j = 0; j < HD; j += 64) {
    float xv = xrow[j + lane];
#pragma unroll
    for (int e = 0; e < NE; e++) acc[e] += xv * rws[e * HD + j + lane];
  }
#pragma unroll
  for (int e = 0; e < NE; e++)
    for (int off = 32; off > 0; off >>= 1) acc[e] += __shfl_xor(acc[e], off, 64);
  if (lane == 0) {
#pragma unroll
    for (int e = 0; e < NE; e++) logits_out[t * NE + e] = acc[e];
    int e0 = 0;
#pragma unroll
    for (int e = 1; e < NE; e++) if (acc[e] > acc[e0]) e0 = e;
    int e1 = (e0 == 0) ? 1 : 0;
#pragma unroll
    for (int e = 0; e < NE; e++)
      if (e != e0 && e != e1 && acc[e] > acc[e1]) e1 = e;
    float b = __expf(acc[e1] - acc[e0]);
    float g0 = 1.f / (1.f + b);
    float g1 = 1.f - g0;
    int p0 = atomicAdd(&counts[e0], 1);
    pair_rowid[e0 * T + p0] = t * 2;
    pair_gate[e0 * T + p0] = g0;
    int p1 = atomicAdd(&counts[e1], 1);
    pair_rowid[e1 * T + p1] = t * 2 + 1;
    pair_gate[e1 * T + p1] = g1;
  }
}

// ---------- GEMM1: h = gelu(x@w1_e^T) * (x@v_e^T) -> hb bf16 ----------
// 128(M)x64(N) tile, BK=64, LDS 32.5KB; grid rowTile-fastest for weight L2 reuse
__global__ __launch_bounds__(256) void gemm1_kernel(
    const unsigned short* __restrict__ xb, const unsigned short* __restrict__ w1b,
    const unsigned short* __restrict__ vb, unsigned short* __restrict__ hb,
    const int* __restrict__ pair_rowid, const int* __restrict__ counts) {
  int e = blockIdx.z;
  int cnt = counts[e];
  int row0 = blockIdx.x * 128;   // rowTile fastest
  if (row0 >= cnt) return;
  __shared__ unsigned short As[128 * 64];
  __shared__ unsigned short B1s[64 * 64];
  __shared__ unsigned short B2s[64 * 64];
  __shared__ int rids[128];
  int tid = threadIdx.x;
  if (tid < 128) {
    int idx = row0 + tid; if (idx > cnt - 1) idx = cnt - 1;
    rids[tid] = pair_rowid[e * T + idx];
  }
  __syncthreads();
  int lane = tid & 63, wid = tid >> 6;
  int wr = wid >> 1, wc = wid & 1;
  int col0 = blockIdx.y * 64;
  int gr = lane >> 3, gc = lane & 7;
  const unsigned short *aA[4], *aB1[2], *aB2[2];
#pragma unroll
  for (int c = 0; c < 4; c++) {
    int row = (c * 4 + wid) * 8 + gr;
    int tok = rids[row] >> 1;
    aA[c] = xb + (size_t)tok * HD + ((gc ^ (row & 7)) * 8);
  }
#pragma unroll
  for (int c = 0; c < 2; c++) {
    int row = (c * 4 + wid) * 8 + gr;
    int kswz = ((gc ^ (row & 7)) * 8);
    aB1[c] = w1b + ((size_t)(e * ID + col0 + row)) * HD + kswz;
    aB2[c] = vb  + ((size_t)(e * ID + col0 + row)) * HD + kswz;
  }
  f32x4 acc1[4][2] = {};
  f32x4 acc3[4][2] = {};
  int mrow = lane & 15, kq = lane >> 4;
  int swzm = mrow & 7;
  for (int kt = 0; kt < HD; kt += 64) {
#pragma unroll
    for (int c = 0; c < 4; c++)
      glds16(aA[c] + kt, &As[(c * 4 + wid) * 512]);
#pragma unroll
    for (int c = 0; c < 2; c++) {
      glds16(aB1[c] + kt, &B1s[(c * 4 + wid) * 512]);
      glds16(aB2[c] + kt, &B2s[(c * 4 + wid) * 512]);
    }
    __syncthreads();
#pragma unroll
    for (int kk = 0; kk < 2; kk++) {
      int g = kk * 4 + kq;
      int ko = ((g ^ swzm) * 8);
      bf16x8 a[4], b1[2], b2[2];
#pragma unroll
      for (int mi = 0; mi < 4; mi++)
        a[mi] = *(const bf16x8*)&As[(wr * 64 + mi * 16 + mrow) * 64 + ko];
#pragma unroll
      for (int ni = 0; ni < 2; ni++) {
        b1[ni] = *(const bf16x8*)&B1s[(wc * 32 + ni * 16 + mrow) * 64 + ko];
        b2[ni] = *(const bf16x8*)&B2s[(wc * 32 + ni * 16 + mrow) * 64 + ko];
      }
#pragma unroll
      for (int mi = 0; mi < 4; mi++)
#pragma unroll
        for (int ni = 0; ni < 2; ni++) {
          acc1[mi][ni] = __builtin_amdgcn_mfma_f32_16x16x32_bf16(a[mi], b1[ni], acc1[mi][ni], 0, 0, 0);
          acc3[mi][ni] = __builtin_amdgcn_mfma_f32_16x16x32_bf16(a[mi], b2[ni], acc3[mi][ni], 0, 0, 0);
        }
    }
    __syncthreads();
  }
  int dcol = lane & 15, drow4 = (lane >> 4) * 4;
#pragma unroll
  for (int mi = 0; mi < 4; mi++)
#pragma unroll
    for (int ni = 0; ni < 2; ni++)
#pragma unroll
      for (int r = 0; r < 4; r++) {
        int lr = wr * 64 + mi * 16 + drow4 + r;
        if (row0 + lr < cnt) {
          float g1v = acc1[mi][ni][r];
          float g3v = acc3[mi][ni][r];
          float hval = 0.5f * g1v * (1.f + erff(g1v * 0.70710678118654752f)) * g3v;
          int rowid = rids[lr];
          hb[(size_t)rowid * ID + col0 + wc * 32 + ni * 16 + dcol] = f2bf(hval);
        }
      }
}

// ---------- GEMM2: y = h @ w2_e^T, gate, atomic-add ----------
// 64x64 tile, BK=64, LDS 16.5KB; grid rowTile-fastest
__global__ __launch_bounds__(256) void gemm2_kernel(
    const unsigned short* __restrict__ hb, const unsigned short* __restrict__ w2b,
    float* __restrict__ out, const int* __restrict__ pair_rowid,
    const float* __restrict__ pair_gate, const int* __restrict__ counts) {
  int e = blockIdx.z;
  int cnt = counts[e];
  int row0 = blockIdx.x * 64;    // rowTile fastest
  if (row0 >= cnt) return;
  __shared__ unsigned short As[64 * 64];
  __shared__ unsigned short Bs[64 * 64];
  __shared__ int rids[64];
  __shared__ float gts[64];
  int tid = threadIdx.x;
  if (tid < 64) {
    int idx = row0 + tid; if (idx > cnt - 1) idx = cnt - 1;
    rids[tid] = pair_rowid[e * T + idx];
    gts[tid] = pair_gate[e * T + idx];
  }
  __syncthreads();
  int lane = tid & 63, wid = tid >> 6;
  int wr = wid >> 1, wc = wid & 1;
  int col0 = blockIdx.y * 64;
  int gr = lane >> 3, gc = lane & 7;
  const unsigned short *aA[2], *aB[2];
#pragma unroll
  for (int c = 0; c < 2; c++) {
    int row = (c * 4 + wid) * 8 + gr;
    int kswz = ((gc ^ (row & 7)) * 8);
    aA[c] = hb  + (size_t)rids[row] * ID + kswz;
    aB[c] = w2b + ((size_t)(e * HD + col0 + row)) * ID + kswz;
  }
  f32x4 acc[2][2] = {};
  int mrow = lane & 15, kq = lane >> 4;
  int swzm = mrow & 7;
  for (int kt = 0; kt < ID; kt += 64) {
#pragma unroll
    for (int c = 0; c < 2; c++) {
      glds16(aA[c] + kt, &As[(c * 4 + wid) * 512]);
      glds16(aB[c] + kt, &Bs[(c * 4 + wid) * 512]);
    }
    __syncthreads();
#pragma unroll
    for (int kk = 0; kk < 2; kk++) {
      int g = kk * 4 + kq;
      int ko = ((g ^ swzm) * 8);
      bf16x8 a[2], b[2];
#pragma unroll
      for (int mi = 0; mi < 2; mi++)
        a[mi] = *(const bf16x8*)&As[(wr * 32 + mi * 16 + mrow) * 64 + ko];
#pragma unroll
      for (int ni = 0; ni < 2; ni++)
        b[ni] = *(const bf16x8*)&Bs[(wc * 32 + ni * 16 + mrow) * 64 + ko];
#pragma unroll
      for (int mi = 0; mi < 2; mi++)
#pragma unroll
        for (int ni = 0; ni < 2; ni++)
          acc[mi][ni] = __builtin_amdgcn_mfma_f32_16x16x32_bf16(a[mi], b[ni], acc[mi][ni], 0, 0, 0);
    }
    __syncthreads();
  }
  int dcol = lane & 15, drow4 = (lane >> 4) * 4;
#pragma unroll
  for (int mi = 0; mi < 2; mi++)
#pragma unroll
    for (int ni = 0; ni < 2; ni++)
#pragma unroll
      for (int r = 0; r < 4; r++) {
        int lr = wr * 32 + mi * 16 + drow4 + r;
        if (row0 + lr < cnt) {
          int tokrow = rids[lr] >> 1;
          float val = gts[lr] * acc[mi][ni][r];
          atomicAdd(&out[(size_t)tokrow * HD + col0 + wc * 32 + ni * 16 + dcol], val);
        }
      }
}

extern "C" void kernel_launch(void* const* d_in, const int* in_sizes, int n_in,
                              void* d_out, int out_size, void* d_ws, size_t ws_size,
                              hipStream_t stream) {
  const float* x  = (const float*)d_in[0];
  const float* rw = (const float*)d_in[1];
  const float* w1 = (const float*)d_in[2];
  const float* v  = (const float*)d_in[3];
  const float* w2 = (const float*)d_in[4];
  float* out = (float*)d_out;
  float* logits_out = out + (size_t)T * HD;

  char* ws = (char*)d_ws;
  unsigned short* xb  = (unsigned short*)(ws);                      // 4 MB
  unsigned short* hb  = (unsigned short*)(ws + (4u << 20));         // 16 MB
  unsigned short* w1b = (unsigned short*)(ws + (20u << 20));        // 32 MB
  unsigned short* vb  = (unsigned short*)(ws + (52u << 20));        // 32 MB
  unsigned short* w2b = (unsigned short*)(ws + (84u << 20));        // 32 MB
  int*   pair_rowid   = (int*)  (ws + (116u << 20));                // 64 KB
  float* pair_gate    = (float*)(ws + (116u << 20) + 65536);        // 64 KB
  int*   counts       = (int*)  (ws + (116u << 20) + 131072);       // 32 B

  hipMemsetAsync(out, 0, (size_t)T * HD * sizeof(float), stream);
  hipMemsetAsync(counts, 0, NE * sizeof(int), stream);

  cast_w_kernel<<<dim3(8192, 3), 256, 0, stream>>>(w1, v, w2, w1b, vb, w2b);
  cast_x_kernel<<<(T * HD) / (256 * 8), 256, 0, stream>>>(x, xb);
  router_kernel<<<T / 4, 256, 0, stream>>>(x, rw, logits_out, pair_rowid,
                                           pair_gate, counts);
  // grid: (rowTile fastest, colTile, expert)
  gemm1_kernel<<<dim3(T / 128, ID / 64, NE), 256, 0, stream>>>(
      xb, w1b, vb, hb, pair_rowid, counts);
  gemm2_kernel<<<dim3(T / 64, HD / 64, NE), 256, 0, stream>>>(
      hb, w2b, out, pair_rowid, pair_gate, counts);
}

// Round 5
// 394.131 us; speedup vs baseline: 1.4478x; 1.4478x over previous
//
#include <hip/hip_runtime.h>
#include <math.h>

#define T 2048
#define HD 1024
#define ID 2048
#define NE 8

typedef short bf16x8 __attribute__((ext_vector_type(8)));
typedef float f32x4 __attribute__((ext_vector_type(4)));
typedef unsigned short u16x8 __attribute__((ext_vector_type(8)));

__device__ __forceinline__ unsigned short f2bf(float f) {
  union { float f; unsigned u; } v; v.f = f;
  unsigned r = v.u + 0x7FFFu + ((v.u >> 16) & 1u);
  return (unsigned short)(r >> 16);
}

__device__ __forceinline__ u16x8 cvt8(float4 a, float4 b) {
  u16x8 o;
  o[0] = f2bf(a.x); o[1] = f2bf(a.y); o[2] = f2bf(a.z); o[3] = f2bf(a.w);
  o[4] = f2bf(b.x); o[5] = f2bf(b.y); o[6] = f2bf(b.z); o[7] = f2bf(b.w);
  return o;
}

// async global->LDS, 16B per lane; LDS dest = wave-uniform base + lane*16
__device__ __forceinline__ void glds16(const unsigned short* g, unsigned short* l) {
  __builtin_amdgcn_global_load_lds(
      (const __attribute__((address_space(1))) unsigned int*)(g),
      (__attribute__((address_space(3))) unsigned int*)(l), 16, 0, 0);
}

// ---------- cast x (fp32) -> xb (bf16) ----------
__global__ __launch_bounds__(256) void cast_x_kernel(
    const float* __restrict__ x, unsigned short* __restrict__ xb) {
  size_t idx = ((size_t)blockIdx.x * 256 + threadIdx.x) * 8;
  float4 f0 = *(const float4*)(x + idx);
  float4 f1 = *(const float4*)(x + idx + 4);
  *(u16x8*)(xb + idx) = cvt8(f0, f1);
}

// ---------- cast weights (fp32) -> bf16, 3 tensors via blockIdx.y ----------
__global__ __launch_bounds__(256) void cast_w_kernel(
    const float* __restrict__ s0, const float* __restrict__ s1,
    const float* __restrict__ s2, unsigned short* __restrict__ d0,
    unsigned short* __restrict__ d1, unsigned short* __restrict__ d2) {
  const float* s; unsigned short* d;
  if (blockIdx.y == 0)      { s = s0; d = d0; }
  else if (blockIdx.y == 1) { s = s1; d = d1; }
  else                      { s = s2; d = d2; }
  size_t idx = ((size_t)blockIdx.x * 256 + threadIdx.x) * 8;
  float4 f0 = *(const float4*)(s + idx);
  float4 f1 = *(const float4*)(s + idx + 4);
  *(u16x8*)(d + idx) = cvt8(f0, f1);
}

// ---------- router ----------
__global__ __launch_bounds__(256) void router_kernel(
    const float* __restrict__ x, const float* __restrict__ rw,
    float* __restrict__ logits_out, int* __restrict__ pair_rowid,
    float* __restrict__ pair_gate, int* __restrict__ counts) {
  __shared__ float rws[NE * HD];
  int tid = threadIdx.x;
  for (int j = tid * 4; j < NE * HD; j += 256 * 4)
    *(float4*)&rws[j] = *(const float4*)&rw[j];
  __syncthreads();
  int wid = tid >> 6, lane = tid & 63;
  int t = blockIdx.x * 4 + wid;
  float acc[NE];
#pragma unroll
  for (int e = 0; e < NE; e++) acc[e] = 0.f;
  const float* xrow = x + (size_t)t * HD;
  for (int j = 0; j < HD; j += 64) {
    float xv = xrow[j + lane];
#pragma unroll
    for (int e = 0; e < NE; e++) acc[e] += xv * rws[e * HD + j + lane];
  }
#pragma unroll
  for (int e = 0; e < NE; e++)
    for (int off = 32; off > 0; off >>= 1) acc[e] += __shfl_xor(acc[e], off, 64);
  if (lane == 0) {
#pragma unroll
    for (int e = 0; e < NE; e++) logits_out[t * NE + e] = acc[e];
    int e0 = 0;
#pragma unroll
    for (int e = 1; e < NE; e++) if (acc[e] > acc[e0]) e0 = e;
    int e1 = (e0 == 0) ? 1 : 0;
#pragma unroll
    for (int e = 0; e < NE; e++)
      if (e != e0 && e != e1 && acc[e] > acc[e1]) e1 = e;
    float b = __expf(acc[e1] - acc[e0]);
    float g0 = 1.f / (1.f + b);
    float g1 = 1.f - g0;
    int p0 = atomicAdd(&counts[e0], 1);
    pair_rowid[e0 * T + p0] = t * 2;
    pair_gate[e0 * T + p0] = g0;
    int p1 = atomicAdd(&counts[e1], 1);
    pair_rowid[e1 * T + p1] = t * 2 + 1;
    pair_gate[e1 * T + p1] = g1;
  }
}

// ---------- GEMM1: h = gelu(x@w1_e^T) * (x@v_e^T) -> hb bf16 ----------
// 128(M)x64(N) tile, BK=64, LDS 32.5KB, no reg cap -> ~120 VGPR, 4 blocks/CU
// grid col-fastest (x=colTile): compulsory-only HBM fetch per R2 evidence
__global__ __launch_bounds__(256) void gemm1_kernel(
    const unsigned short* __restrict__ xb, const unsigned short* __restrict__ w1b,
    const unsigned short* __restrict__ vb, unsigned short* __restrict__ hb,
    const int* __restrict__ pair_rowid, const int* __restrict__ counts) {
  int e = blockIdx.z;
  int cnt = counts[e];
  int row0 = blockIdx.y * 128;
  if (row0 >= cnt) return;
  __shared__ unsigned short As[128 * 64];
  __shared__ unsigned short B1s[64 * 64];
  __shared__ unsigned short B2s[64 * 64];
  __shared__ int rids[128];
  int tid = threadIdx.x;
  if (tid < 128) {
    int idx = row0 + tid; if (idx > cnt - 1) idx = cnt - 1;
    rids[tid] = pair_rowid[e * T + idx];
  }
  __syncthreads();
  int lane = tid & 63, wid = tid >> 6;
  int wr = wid >> 1, wc = wid & 1;
  int col0 = blockIdx.x * 64;
  int gr = lane >> 3, gc = lane & 7;
  const unsigned short *aA[4], *aB1[2], *aB2[2];
#pragma unroll
  for (int c = 0; c < 4; c++) {
    int row = (c * 4 + wid) * 8 + gr;
    int tok = rids[row] >> 1;
    aA[c] = xb + (size_t)tok * HD + ((gc ^ (row & 7)) * 8);
  }
#pragma unroll
  for (int c = 0; c < 2; c++) {
    int row = (c * 4 + wid) * 8 + gr;
    int kswz = ((gc ^ (row & 7)) * 8);
    aB1[c] = w1b + ((size_t)(e * ID + col0 + row)) * HD + kswz;
    aB2[c] = vb  + ((size_t)(e * ID + col0 + row)) * HD + kswz;
  }
  f32x4 acc1[4][2] = {};
  f32x4 acc3[4][2] = {};
  int mrow = lane & 15, kq = lane >> 4;
  int swzm = mrow & 7;
  for (int kt = 0; kt < HD; kt += 64) {
#pragma unroll
    for (int c = 0; c < 4; c++)
      glds16(aA[c] + kt, &As[(c * 4 + wid) * 512]);
#pragma unroll
    for (int c = 0; c < 2; c++) {
      glds16(aB1[c] + kt, &B1s[(c * 4 + wid) * 512]);
      glds16(aB2[c] + kt, &B2s[(c * 4 + wid) * 512]);
    }
    __syncthreads();
#pragma unroll
    for (int kk = 0; kk < 2; kk++) {
      int g = kk * 4 + kq;
      int ko = ((g ^ swzm) * 8);
      bf16x8 a[4], b1[2], b2[2];
#pragma unroll
      for (int mi = 0; mi < 4; mi++)
        a[mi] = *(const bf16x8*)&As[(wr * 64 + mi * 16 + mrow) * 64 + ko];
#pragma unroll
      for (int ni = 0; ni < 2; ni++) {
        b1[ni] = *(const bf16x8*)&B1s[(wc * 32 + ni * 16 + mrow) * 64 + ko];
        b2[ni] = *(const bf16x8*)&B2s[(wc * 32 + ni * 16 + mrow) * 64 + ko];
      }
#pragma unroll
      for (int mi = 0; mi < 4; mi++)
#pragma unroll
        for (int ni = 0; ni < 2; ni++) {
          acc1[mi][ni] = __builtin_amdgcn_mfma_f32_16x16x32_bf16(a[mi], b1[ni], acc1[mi][ni], 0, 0, 0);
          acc3[mi][ni] = __builtin_amdgcn_mfma_f32_16x16x32_bf16(a[mi], b2[ni], acc3[mi][ni], 0, 0, 0);
        }
    }
    __syncthreads();
  }
  int dcol = lane & 15, drow4 = (lane >> 4) * 4;
#pragma unroll
  for (int mi = 0; mi < 4; mi++)
#pragma unroll
    for (int ni = 0; ni < 2; ni++)
#pragma unroll
      for (int r = 0; r < 4; r++) {
        int lr = wr * 64 + mi * 16 + drow4 + r;
        if (row0 + lr < cnt) {
          float g1v = acc1[mi][ni][r];
          float g3v = acc3[mi][ni][r];
          float hval = 0.5f * g1v * (1.f + erff(g1v * 0.70710678118654752f)) * g3v;
          int rowid = rids[lr];
          hb[(size_t)rowid * ID + col0 + wc * 32 + ni * 16 + dcol] = f2bf(hval);
        }
      }
}

// ---------- GEMM2: y = h @ w2_e^T, gate, atomic-add ----------
// 64x64 tile, BK=64, LDS 16.5KB, no reg cap; grid col-fastest
__global__ __launch_bounds__(256) void gemm2_kernel(
    const unsigned short* __restrict__ hb, const unsigned short* __restrict__ w2b,
    float* __restrict__ out, const int* __restrict__ pair_rowid,
    const float* __restrict__ pair_gate, const int* __restrict__ counts) {
  int e = blockIdx.z;
  int cnt = counts[e];
  int row0 = blockIdx.y * 64;
  if (row0 >= cnt) return;
  __shared__ unsigned short As[64 * 64];
  __shared__ unsigned short Bs[64 * 64];
  __shared__ int rids[64];
  __shared__ float gts[64];
  int tid = threadIdx.x;
  if (tid < 64) {
    int idx = row0 + tid; if (idx > cnt - 1) idx = cnt - 1;
    rids[tid] = pair_rowid[e * T + idx];
    gts[tid] = pair_gate[e * T + idx];
  }
  __syncthreads();
  int lane = tid & 63, wid = tid >> 6;
  int wr = wid >> 1, wc = wid & 1;
  int col0 = blockIdx.x * 64;
  int gr = lane >> 3, gc = lane & 7;
  const unsigned short *aA[2], *aB[2];
#pragma unroll
  for (int c = 0; c < 2; c++) {
    int row = (c * 4 + wid) * 8 + gr;
    int kswz = ((gc ^ (row & 7)) * 8);
    aA[c] = hb  + (size_t)rids[row] * ID + kswz;
    aB[c] = w2b + ((size_t)(e * HD + col0 + row)) * ID + kswz;
  }
  f32x4 acc[2][2] = {};
  int mrow = lane & 15, kq = lane >> 4;
  int swzm = mrow & 7;
  for (int kt = 0; kt < ID; kt += 64) {
#pragma unroll
    for (int c = 0; c < 2; c++) {
      glds16(aA[c] + kt, &As[(c * 4 + wid) * 512]);
      glds16(aB[c] + kt, &Bs[(c * 4 + wid) * 512]);
    }
    __syncthreads();
#pragma unroll
    for (int kk = 0; kk < 2; kk++) {
      int g = kk * 4 + kq;
      int ko = ((g ^ swzm) * 8);
      bf16x8 a[2], b[2];
#pragma unroll
      for (int mi = 0; mi < 2; mi++)
        a[mi] = *(const bf16x8*)&As[(wr * 32 + mi * 16 + mrow) * 64 + ko];
#pragma unroll
      for (int ni = 0; ni < 2; ni++)
        b[ni] = *(const bf16x8*)&Bs[(wc * 32 + ni * 16 + mrow) * 64 + ko];
#pragma unroll
      for (int mi = 0; mi < 2; mi++)
#pragma unroll
        for (int ni = 0; ni < 2; ni++)
          acc[mi][ni] = __builtin_amdgcn_mfma_f32_16x16x32_bf16(a[mi], b[ni], acc[mi][ni], 0, 0, 0);
    }
    __syncthreads();
  }
  int dcol = lane & 15, drow4 = (lane >> 4) * 4;
#pragma unroll
  for (int mi = 0; mi < 2; mi++)
#pragma unroll
    for (int ni = 0; ni < 2; ni++)
#pragma unroll
      for (int r = 0; r < 4; r++) {
        int lr = wr * 32 + mi * 16 + drow4 + r;
        if (row0 + lr < cnt) {
          int tokrow = rids[lr] >> 1;
          float val = gts[lr] * acc[mi][ni][r];
          atomicAdd(&out[(size_t)tokrow * HD + col0 + wc * 32 + ni * 16 + dcol], val);
        }
      }
}

extern "C" void kernel_launch(void* const* d_in, const int* in_sizes, int n_in,
                              void* d_out, int out_size, void* d_ws, size_t ws_size,
                              hipStream_t stream) {
  const float* x  = (const float*)d_in[0];
  const float* rw = (const float*)d_in[1];
  const float* w1 = (const float*)d_in[2];
  const float* v  = (const float*)d_in[3];
  const float* w2 = (const float*)d_in[4];
  float* out = (float*)d_out;
  float* logits_out = out + (size_t)T * HD;

  char* ws = (char*)d_ws;
  unsigned short* xb  = (unsigned short*)(ws);                      // 4 MB
  unsigned short* hb  = (unsigned short*)(ws + (4u << 20));         // 16 MB
  unsigned short* w1b = (unsigned short*)(ws + (20u << 20));        // 32 MB
  unsigned short* vb  = (unsigned short*)(ws + (52u << 20));        // 32 MB
  unsigned short* w2b = (unsigned short*)(ws + (84u << 20));        // 32 MB
  int*   pair_rowid   = (int*)  (ws + (116u << 20));                // 64 KB
  float* pair_gate    = (float*)(ws + (116u << 20) + 65536);        // 64 KB
  int*   counts       = (int*)  (ws + (116u << 20) + 131072);       // 32 B

  hipMemsetAsync(out, 0, (size_t)T * HD * sizeof(float), stream);
  hipMemsetAsync(counts, 0, NE * sizeof(int), stream);

  cast_w_kernel<<<dim3(8192, 3), 256, 0, stream>>>(w1, v, w2, w1b, vb, w2b);
  cast_x_kernel<<<(T * HD) / (256 * 8), 256, 0, stream>>>(x, xb);
  router_kernel<<<T / 4, 256, 0, stream>>>(x, rw, logits_out, pair_rowid,
                                           pair_gate, counts);
  // grid: (colTile fastest, rowTile, expert)
  gemm1_kernel<<<dim3(ID / 64, T / 128, NE), 256, 0, stream>>>(
      xb, w1b, vb, hb, pair_rowid, counts);
  gemm2_kernel<<<dim3(HD / 64, T / 64, NE), 256, 0, stream>>>(
      hb, w2b, out, pair_rowid, pair_gate, counts);
}

// Round 6
// 367.533 us; speedup vs baseline: 1.5526x; 1.0724x over previous
//
#include <hip/hip_runtime.h>
#include <math.h>

#define T 2048
#define HD 1024
#define ID 2048
#define NE 8

typedef short bf16x8 __attribute__((ext_vector_type(8)));
typedef float f32x4 __attribute__((ext_vector_type(4)));
typedef unsigned short u16x8 __attribute__((ext_vector_type(8)));

__device__ __forceinline__ unsigned short f2bf(float f) {
  union { float f; unsigned u; } v; v.f = f;
  unsigned r = v.u + 0x7FFFu + ((v.u >> 16) & 1u);
  return (unsigned short)(r >> 16);
}

__device__ __forceinline__ u16x8 cvt8(float4 a, float4 b) {
  u16x8 o;
  o[0] = f2bf(a.x); o[1] = f2bf(a.y); o[2] = f2bf(a.z); o[3] = f2bf(a.w);
  o[4] = f2bf(b.x); o[5] = f2bf(b.y); o[6] = f2bf(b.z); o[7] = f2bf(b.w);
  return o;
}

// cast 16 fp32 -> 16 bf16 per thread; block covers 4096 elems
__device__ __forceinline__ void cast_chunk16(const float* __restrict__ s,
                                             unsigned short* __restrict__ d,
                                             size_t base) {
  size_t idx = base + (size_t)threadIdx.x * 16;
  float4 f0 = *(const float4*)(s + idx);
  float4 f1 = *(const float4*)(s + idx + 4);
  float4 f2 = *(const float4*)(s + idx + 8);
  float4 f3 = *(const float4*)(s + idx + 12);
  *(u16x8*)(d + idx) = cvt8(f0, f1);
  *(u16x8*)(d + idx + 8) = cvt8(f2, f3);
}

// async global->LDS, 16B per lane; LDS dest = wave-uniform base + lane*16
__device__ __forceinline__ void glds16(const unsigned short* g, unsigned short* l) {
  __builtin_amdgcn_global_load_lds(
      (const __attribute__((address_space(1))) unsigned int*)(g),
      (__attribute__((address_space(3))) unsigned int*)(l), 16, 0, 0);
}

// ---------- prep: router (blocks 0..511) + cast_x (512..1023) +
//                  cast w1,v (1024..9215), 16 elems/thread ----------
__global__ __launch_bounds__(256) void prep_kernel(
    const float* __restrict__ x, const float* __restrict__ rw,
    const float* __restrict__ w1, const float* __restrict__ v,
    unsigned short* __restrict__ xb, unsigned short* __restrict__ w1b,
    unsigned short* __restrict__ vb, float* __restrict__ logits_out,
    int* __restrict__ pair_rowid, float* __restrict__ pair_gate,
    int* __restrict__ counts) {
  int bx = blockIdx.x;
  if (bx >= 1024) {
    int cid = bx - 1024;                 // [0, 8192)
    const float* s = (cid < 4096) ? w1 : v;
    unsigned short* d = (cid < 4096) ? w1b : vb;
    cast_chunk16(s, d, (size_t)(cid & 4095) * 4096);
    return;
  }
  if (bx >= 512) {
    cast_chunk16(x, xb, (size_t)(bx - 512) * 4096);
    return;
  }
  // router
  __shared__ float rws[NE * HD];
  int tid = threadIdx.x;
  for (int j = tid * 4; j < NE * HD; j += 256 * 4)
    *(float4*)&rws[j] = *(const float4*)&rw[j];
  __syncthreads();
  int wid = tid >> 6, lane = tid & 63;
  int t = bx * 4 + wid;
  float acc[NE];
#pragma unroll
  for (int e = 0; e < NE; e++) acc[e] = 0.f;
  const float* xrow = x + (size_t)t * HD;
  for (int j = 0; j < HD; j += 64) {
    float xv = xrow[j + lane];
#pragma unroll
    for (int e = 0; e < NE; e++) acc[e] += xv * rws[e * HD + j + lane];
  }
#pragma unroll
  for (int e = 0; e < NE; e++)
    for (int off = 32; off > 0; off >>= 1) acc[e] += __shfl_xor(acc[e], off, 64);
  if (lane == 0) {
#pragma unroll
    for (int e = 0; e < NE; e++) logits_out[t * NE + e] = acc[e];
    int e0 = 0;
#pragma unroll
    for (int e = 1; e < NE; e++) if (acc[e] > acc[e0]) e0 = e;
    int e1 = (e0 == 0) ? 1 : 0;
#pragma unroll
    for (int e = 0; e < NE; e++)
      if (e != e0 && e != e1 && acc[e] > acc[e1]) e1 = e;
    float b = __expf(acc[e1] - acc[e0]);
    float g0 = 1.f / (1.f + b);
    float g1 = 1.f - g0;
    int p0 = atomicAdd(&counts[e0], 1);
    pair_rowid[e0 * T + p0] = t * 2;
    pair_gate[e0 * T + p0] = g0;
    int p1 = atomicAdd(&counts[e1], 1);
    pair_rowid[e1 * T + p1] = t * 2 + 1;
    pair_gate[e1 * T + p1] = g1;
  }
}

// ---------- GEMM1 + fused w2 cast ----------
// blockIdx.x < 32: 128(M)x64(N) tile GEMM1, BK=64, col-fastest
// blockIdx.x >= 32: cast a 4096-elem chunk of w2 -> w2b (done before gemm2)
__global__ __launch_bounds__(256) void gemm1_kernel(
    const unsigned short* __restrict__ xb, const unsigned short* __restrict__ w1b,
    const unsigned short* __restrict__ vb, unsigned short* __restrict__ hb,
    const float* __restrict__ w2, unsigned short* __restrict__ w2b,
    const int* __restrict__ pair_rowid, const int* __restrict__ counts) {
  if (blockIdx.x >= 32) {
    int cid = (blockIdx.x - 32) + 32 * (blockIdx.y + 16 * blockIdx.z); // [0,4096)
    cast_chunk16(w2, w2b, (size_t)cid * 4096);
    return;
  }
  int e = blockIdx.z;
  int cnt = counts[e];
  int row0 = blockIdx.y * 128;
  if (row0 >= cnt) return;
  __shared__ unsigned short As[128 * 64];
  __shared__ unsigned short B1s[64 * 64];
  __shared__ unsigned short B2s[64 * 64];
  __shared__ int rids[128];
  int tid = threadIdx.x;
  if (tid < 128) {
    int idx = row0 + tid; if (idx > cnt - 1) idx = cnt - 1;
    rids[tid] = pair_rowid[e * T + idx];
  }
  __syncthreads();
  int lane = tid & 63, wid = tid >> 6;
  int wr = wid >> 1, wc = wid & 1;
  int col0 = blockIdx.x * 64;
  int gr = lane >> 3, gc = lane & 7;
  const unsigned short *aA[4], *aB1[2], *aB2[2];
#pragma unroll
  for (int c = 0; c < 4; c++) {
    int row = (c * 4 + wid) * 8 + gr;
    int tok = rids[row] >> 1;
    aA[c] = xb + (size_t)tok * HD + ((gc ^ (row & 7)) * 8);
  }
#pragma unroll
  for (int c = 0; c < 2; c++) {
    int row = (c * 4 + wid) * 8 + gr;
    int kswz = ((gc ^ (row & 7)) * 8);
    aB1[c] = w1b + ((size_t)(e * ID + col0 + row)) * HD + kswz;
    aB2[c] = vb  + ((size_t)(e * ID + col0 + row)) * HD + kswz;
  }
  f32x4 acc1[4][2] = {};
  f32x4 acc3[4][2] = {};
  int mrow = lane & 15, kq = lane >> 4;
  int swzm = mrow & 7;
  for (int kt = 0; kt < HD; kt += 64) {
#pragma unroll
    for (int c = 0; c < 4; c++)
      glds16(aA[c] + kt, &As[(c * 4 + wid) * 512]);
#pragma unroll
    for (int c = 0; c < 2; c++) {
      glds16(aB1[c] + kt, &B1s[(c * 4 + wid) * 512]);
      glds16(aB2[c] + kt, &B2s[(c * 4 + wid) * 512]);
    }
    __syncthreads();
#pragma unroll
    for (int kk = 0; kk < 2; kk++) {
      int g = kk * 4 + kq;
      int ko = ((g ^ swzm) * 8);
      bf16x8 a[4], b1[2], b2[2];
#pragma unroll
      for (int mi = 0; mi < 4; mi++)
        a[mi] = *(const bf16x8*)&As[(wr * 64 + mi * 16 + mrow) * 64 + ko];
#pragma unroll
      for (int ni = 0; ni < 2; ni++) {
        b1[ni] = *(const bf16x8*)&B1s[(wc * 32 + ni * 16 + mrow) * 64 + ko];
        b2[ni] = *(const bf16x8*)&B2s[(wc * 32 + ni * 16 + mrow) * 64 + ko];
      }
#pragma unroll
      for (int mi = 0; mi < 4; mi++)
#pragma unroll
        for (int ni = 0; ni < 2; ni++) {
          acc1[mi][ni] = __builtin_amdgcn_mfma_f32_16x16x32_bf16(a[mi], b1[ni], acc1[mi][ni], 0, 0, 0);
          acc3[mi][ni] = __builtin_amdgcn_mfma_f32_16x16x32_bf16(a[mi], b2[ni], acc3[mi][ni], 0, 0, 0);
        }
    }
    __syncthreads();
  }
  int dcol = lane & 15, drow4 = (lane >> 4) * 4;
#pragma unroll
  for (int mi = 0; mi < 4; mi++)
#pragma unroll
    for (int ni = 0; ni < 2; ni++)
#pragma unroll
      for (int r = 0; r < 4; r++) {
        int lr = wr * 64 + mi * 16 + drow4 + r;
        if (row0 + lr < cnt) {
          float g1v = acc1[mi][ni][r];
          float g3v = acc3[mi][ni][r];
          float hval = 0.5f * g1v * (1.f + erff(g1v * 0.70710678118654752f)) * g3v;
          int rowid = rids[lr];
          hb[(size_t)rowid * ID + col0 + wc * 32 + ni * 16 + dcol] = f2bf(hval);
        }
      }
}

// ---------- GEMM2: y = h @ w2_e^T, gate, atomic-add ----------
// 64x64 tile, BK=64, col-fastest
__global__ __launch_bounds__(256) void gemm2_kernel(
    const unsigned short* __restrict__ hb, const unsigned short* __restrict__ w2b,
    float* __restrict__ out, const int* __restrict__ pair_rowid,
    const float* __restrict__ pair_gate, const int* __restrict__ counts) {
  int e = blockIdx.z;
  int cnt = counts[e];
  int row0 = blockIdx.y * 64;
  if (row0 >= cnt) return;
  __shared__ unsigned short As[64 * 64];
  __shared__ unsigned short Bs[64 * 64];
  __shared__ int rids[64];
  __shared__ float gts[64];
  int tid = threadIdx.x;
  if (tid < 64) {
    int idx = row0 + tid; if (idx > cnt - 1) idx = cnt - 1;
    rids[tid] = pair_rowid[e * T + idx];
    gts[tid] = pair_gate[e * T + idx];
  }
  __syncthreads();
  int lane = tid & 63, wid = tid >> 6;
  int wr = wid >> 1, wc = wid & 1;
  int col0 = blockIdx.x * 64;
  int gr = lane >> 3, gc = lane & 7;
  const unsigned short *aA[2], *aB[2];
#pragma unroll
  for (int c = 0; c < 2; c++) {
    int row = (c * 4 + wid) * 8 + gr;
    int kswz = ((gc ^ (row & 7)) * 8);
    aA[c] = hb  + (size_t)rids[row] * ID + kswz;
    aB[c] = w2b + ((size_t)(e * HD + col0 + row)) * ID + kswz;
  }
  f32x4 acc[2][2] = {};
  int mrow = lane & 15, kq = lane >> 4;
  int swzm = mrow & 7;
  for (int kt = 0; kt < ID; kt += 64) {
#pragma unroll
    for (int c = 0; c < 2; c++) {
      glds16(aA[c] + kt, &As[(c * 4 + wid) * 512]);
      glds16(aB[c] + kt, &Bs[(c * 4 + wid) * 512]);
    }
    __syncthreads();
#pragma unroll
    for (int kk = 0; kk < 2; kk++) {
      int g = kk * 4 + kq;
      int ko = ((g ^ swzm) * 8);
      bf16x8 a[2], b[2];
#pragma unroll
      for (int mi = 0; mi < 2; mi++)
        a[mi] = *(const bf16x8*)&As[(wr * 32 + mi * 16 + mrow) * 64 + ko];
#pragma unroll
      for (int ni = 0; ni < 2; ni++)
        b[ni] = *(const bf16x8*)&Bs[(wc * 32 + ni * 16 + mrow) * 64 + ko];
#pragma unroll
      for (int mi = 0; mi < 2; mi++)
#pragma unroll
        for (int ni = 0; ni < 2; ni++)
          acc[mi][ni] = __builtin_amdgcn_mfma_f32_16x16x32_bf16(a[mi], b[ni], acc[mi][ni], 0, 0, 0);
    }
    __syncthreads();
  }
  int dcol = lane & 15, drow4 = (lane >> 4) * 4;
#pragma unroll
  for (int mi = 0; mi < 2; mi++)
#pragma unroll
    for (int ni = 0; ni < 2; ni++)
#pragma unroll
      for (int r = 0; r < 4; r++) {
        int lr = wr * 32 + mi * 16 + drow4 + r;
        if (row0 + lr < cnt) {
          int tokrow = rids[lr] >> 1;
          float val = gts[lr] * acc[mi][ni][r];
          atomicAdd(&out[(size_t)tokrow * HD + col0 + wc * 32 + ni * 16 + dcol], val);
        }
      }
}

extern "C" void kernel_launch(void* const* d_in, const int* in_sizes, int n_in,
                              void* d_out, int out_size, void* d_ws, size_t ws_size,
                              hipStream_t stream) {
  const float* x  = (const float*)d_in[0];
  const float* rw = (const float*)d_in[1];
  const float* w1 = (const float*)d_in[2];
  const float* v  = (const float*)d_in[3];
  const float* w2 = (const float*)d_in[4];
  float* out = (float*)d_out;
  float* logits_out = out + (size_t)T * HD;

  char* ws = (char*)d_ws;
  unsigned short* xb  = (unsigned short*)(ws);                      // 4 MB
  unsigned short* hb  = (unsigned short*)(ws + (4u << 20));         // 16 MB
  unsigned short* w1b = (unsigned short*)(ws + (20u << 20));        // 32 MB
  unsigned short* vb  = (unsigned short*)(ws + (52u << 20));        // 32 MB
  unsigned short* w2b = (unsigned short*)(ws + (84u << 20));        // 32 MB
  int*   pair_rowid   = (int*)  (ws + (116u << 20));                // 64 KB
  float* pair_gate    = (float*)(ws + (116u << 20) + 65536);        // 64 KB
  int*   counts       = (int*)  (ws + (116u << 20) + 131072);       // 32 B

  hipMemsetAsync(out, 0, (size_t)T * HD * sizeof(float), stream);
  hipMemsetAsync(counts, 0, NE * sizeof(int), stream);

  // prep: 512 router blocks + 512 x-cast + 8192 w1/v-cast
  prep_kernel<<<9216, 256, 0, stream>>>(x, rw, w1, v, xb, w1b, vb,
                                        logits_out, pair_rowid, pair_gate,
                                        counts);
  // gemm1 (x<32) + w2 cast (x>=32, 4096 blocks, ready before gemm2 by stream order)
  gemm1_kernel<<<dim3(ID / 64 + 32, T / 128, NE), 256, 0, stream>>>(
      xb, w1b, vb, hb, w2, w2b, pair_rowid, counts);
  gemm2_kernel<<<dim3(HD / 64, T / 64, NE), 256, 0, stream>>>(
      hb, w2b, out, pair_rowid, pair_gate, counts);
}